// Round 7
// baseline (197.430 us; speedup 1.0000x reference)
//
#include <hip/hip_runtime.h>

#define N_NODES 50000
#define N_EDGES 1600000
#define NB 782            // buckets of 64 dst nodes: ceil(50000/64)
#define NBB 256           // binning blocks
#define CHUNK 6250        // N_EDGES / NBB (exact, even)
#define CAP 2560          // fixed bucket capacity (mean 2046 + 11 sigma)
#define SCAP 3072         // srcp per-bucket capacity (CAP + pad slack)
#define ZROW 50000        // dummy src row (all zeros) for padding
#define NTILES 3125       // 50000 / 16 exact

typedef unsigned short ushort_t;
typedef _Float16 v8h __attribute__((ext_vector_type(8)));
typedef _Float16 v4h __attribute__((ext_vector_type(4)));
typedef float f32x4_t __attribute__((ext_vector_type(4)));

// MEASUREMENT ROUND (minimal diff from verified r4 source): ONLY k_agg runs
// its idempotent body 3x.  dur_us - 157.8 = 2*t_agg, and the profiled k_agg
// dispatch (3*t_agg) cracks the 44.5us top-5 floor whenever t_agg > 15us.
// Everything else byte-identical to the verified 157.8us kernel.

// ========== fused binning + weight prep (independent block families) ======
__global__ __launch_bounds__(256) void k_binw(
    const int* __restrict__ ei, int* __restrict__ gcur, int* __restrict__ bins,
    const float* __restrict__ Wz, const float* __restrict__ bz,
    const float* __restrict__ Wlz, const float* __restrict__ blz,
    const float* __restrict__ Wh, const float* __restrict__ bh,
    const float* __restrict__ Wlh, const float* __restrict__ blh,
    const float* __restrict__ Wout, float* __restrict__ B2f,
    _Float16* __restrict__ Bzh, _Float16* __restrict__ Bwo) {
  __shared__ int arena[8320];   // bin: 2*NB+CHUNK=7814 ints; wprep: 8320 floats
  int tid = threadIdx.x, blk = blockIdx.x;
  if (blk < NBB) {
    int* h    = arena;          // 782
    int* segb = arena + NB;     // 782
    int* pk   = arena + 2 * NB; // 6250
    for (int i = tid; i < NB; i += 256) h[i] = 0;
    __syncthreads();
    const int2* s2 = (const int2*)(ei + blk * CHUNK);
    const int2* d2 = (const int2*)(ei + N_EDGES + blk * CHUNK);
    for (int i = tid; i < CHUNK / 2; i += 256) {
      int2 s = s2[i];
      int2 d = d2[i];
      pk[2 * i]     = s.x | ((d.x & 63) << 16) | ((d.x >> 6) << 22);
      pk[2 * i + 1] = s.y | ((d.y & 63) << 16) | ((d.y >> 6) << 22);
      atomicAdd(&h[d.x >> 6], 1);
      atomicAdd(&h[d.y >> 6], 1);
    }
    __syncthreads();
    for (int b = tid; b < NB; b += 256) {
      int c = h[b];
      segb[b] = c ? atomicAdd(&gcur[b], c) : 0;
      h[b] = 0;                       // reuse as local cursor
    }
    __syncthreads();
    for (int i = tid; i < CHUNK; i += 256) {
      int v = pk[i];
      int b = (unsigned)v >> 22;
      int p = atomicAdd(&h[b], 1);
      bins[b * CAP + segb[b] + p] = v & 0x3FFFFF;   // src | dl<<16
    }
  } else {
    // weight prep: wblk 0-3 z-path, 4-7 h-path; ntile = wblk&3
    int wblk = blk - NBB;
    float* A  = (float*)arena;           // 64x65
    float* Bm = (float*)(arena + 4160);  // 64x65
    bool zpath = wblk < 4;
    const float* Wsrc = zpath ? Wz : Wh;
    const float* Lsrc = zpath ? Wlz : Wlh;
    for (int idx = tid; idx < 4096; idx += 256) {
      A[(idx >> 6) * 65 + (idx & 63)] = Wsrc[idx];
      Bm[(idx >> 6) * 65 + (idx & 63)] = Lsrc[idx];
    }
    __syncthreads();
    int lane = (tid >> 1) & 63;
    int j0 = (tid & 1) * 4;
    int ks = (tid >> 7) & 1;
    int k0 = ks * 32 + ((lane >> 4) << 3) + j0;
    int col = (wblk & 3) * 16 + (lane & 15);
    float a0 = 0.f, a1 = 0.f, a2 = 0.f, a3 = 0.f;
    for (int q = 0; q < 64; ++q) {
      float bv = Bm[q * 65 + col];
      a0 = fmaf(A[k0 * 65 + q], bv, a0);
      a1 = fmaf(A[(k0 + 1) * 65 + q], bv, a1);
      a2 = fmaf(A[(k0 + 2) * 65 + q], bv, a2);
      a3 = fmaf(A[(k0 + 3) * 65 + q], bv, a3);
    }
    int tb = wblk * 1024 + tid * 4;
    v4h o; o[0] = (_Float16)a0; o[1] = (_Float16)a1;
    o[2] = (_Float16)a2; o[3] = (_Float16)a3;
    *(v4h*)(Bzh + tb) = o;
    if ((wblk == 0 || wblk == 4) && tid < 64) {
      float v = zpath ? blz[tid] : blh[tid];
      const float* bb = zpath ? bz : bh;
      for (int q = 0; q < 64; ++q) v = fmaf(bb[q], Bm[q * 65 + tid], v);
      B2f[tid * 2 + (zpath ? 0 : 1)] = v;
    }
    if (wblk == 1) {
      for (int e2 = 0; e2 < 12; ++e2) {
        int t2 = tid * 12 + e2;
        int ln = (t2 >> 3) & 63, j = t2 & 7;
        int ntile = t2 >> 10, ks2 = (t2 >> 9) & 1;
        int n = ntile * 16 + (ln & 15);
        int k = ks2 * 32 + ((ln >> 4) << 3) + j;
        Bwo[t2] = (_Float16)((n < 45) ? Wout[k * 45 + n] : 0.f);
      }
    }
  }
}

// ---------------- per-bucket sort -> padded per-node CSR + dinv + xp -------
__global__ __launch_bounds__(256, 4) void k_sort(
    const int* __restrict__ bins, const int* __restrict__ gcur,
    const float* __restrict__ x,
    ushort_t* __restrict__ srcp, int2* __restrict__ rowiv,
    float* __restrict__ dinv, _Float16* __restrict__ xp) {
  __shared__ int dg[64], lo[64], cur[64];
  __shared__ float sdin[64];
  __shared__ int Tsh;
  __shared__ ushort_t buf[8192];
  int tid = threadIdx.x, b = blockIdx.x;
  int start = b * CAP, end = start + gcur[b];
  if (tid < 64) dg[tid] = 0;
  __syncthreads();
  for (int i = start + tid; i < end; i += 256)
    atomicAdd(&dg[bins[i] >> 16], 1);
  __syncthreads();
  int pdv = 0;
  if (tid < 64) { pdv = (dg[tid] + 7) & ~7; lo[tid] = pdv; }
  __syncthreads();
  for (int off = 1; off < 64; off <<= 1) {
    int u = 0;
    if (tid < 64 && tid >= off) u = lo[tid - off];
    __syncthreads();
    if (tid < 64) lo[tid] += u;
    __syncthreads();
  }
  int ex = 0;
  if (tid < 64) {
    ex = lo[tid] - pdv;       // exclusive padded offset
    cur[tid] = ex;
    if (tid == 63) Tsh = lo[63];
  }
  __syncthreads();
  int T = Tsh;
  int base = b * SCAP;        // fixed per-bucket srcp region
  for (int i = tid; i < T; i += 256) buf[i] = (ushort_t)ZROW;
  __syncthreads();
  for (int i = start + tid; i < end; i += 256) {
    int v = bins[i];
    int dl = v >> 16;
    int p = atomicAdd(&cur[dl], 1);
    buf[p] = (ushort_t)(v & 0xFFFF);
  }
  __syncthreads();
  for (int i = tid; i < T; i += 256) srcp[base + i] = buf[i];
  if (tid < 64) {
    int v = b * 64 + tid;
    if (v < N_NODES) {
      rowiv[v] = make_int2(base + ex, pdv);
      float dv = rsqrtf((float)dg[tid] + 2.0f);
      dinv[v] = dv;
      sdin[tid] = dv;
    } else {
      sdin[tid] = 0.f;
    }
  }
  __syncthreads();
  // vectorized x -> xp (float4 in, v4h out)
  const float4* x4 = (const float4*)x;
  int base4 = b * 1024;           // float4 index of bucket start
  int nb64 = b * 4096;            // half index of bucket start
  for (int idx = tid; idx < 1024; idx += 256) {
    int row = idx >> 4;           // 16 float4 per 64-ch row
    int v = b * 64 + row;
    if (v < N_NODES) {
      float4 xv = x4[base4 + idx];
      float s = sdin[row];
      v4h o;
      o[0] = (_Float16)(s * xv.x); o[1] = (_Float16)(s * xv.y);
      o[2] = (_Float16)(s * xv.z); o[3] = (_Float16)(s * xv.w);
      *(v4h*)(xp + nb64 + idx * 4) = o;
    }
  }
  if (b == 0 && tid < 64) xp[ZROW * 64 + tid] = (_Float16)0.f;
}

// ------- gather: 8 lanes x 16B per edge, 8 edges/group, 2-slot pipeline ----
// MEASUREMENT: body runs 3x (idempotent; reads srcp/rowiv/dinv/xp only,
// none aliased with its sxg output; rewrites identical values).
__global__ __launch_bounds__(256, 8) void k_agg(
    const ushort_t* __restrict__ srcp, const int2* __restrict__ rowiv,
    const float* __restrict__ dinv, const _Float16* __restrict__ xp,
    _Float16* __restrict__ sxg) {
  int tid = threadIdx.x;
  int lane = tid & 63;
  int grp = lane >> 3;          // edge slot 0..7 within a group of 8
  int chOff = (lane & 7) << 3;  // channels (lane&7)*8 .. +7
  int w = blockIdx.x * 4 + (tid >> 6);
  int nw = gridDim.x * 4;
  for (int rep = 0; rep < 3; ++rep) {   // x3 for timing split / visibility
  for (int v = w; v < N_NODES; v += nw) {
    int vu = __builtin_amdgcn_readfirstlane(v);
    int2 ri = rowiv[vu];
    int beg = ri.x, pd = ri.y;    // pd multiple of 8
    float accA[8], accB[8];
    #pragma unroll
    for (int j = 0; j < 8; ++j) { accA[j] = 0.f; accB[j] = 0.f; }
    for (int e = beg; e < beg + pd; e += 64) {
      int rem = beg + pd - e;
      int m = rem < 64 ? rem : 64;   // multiple of 8
      int sl = (lane < m) ? (int)srcp[e + lane] : ZROW;
      int mg = m >> 3;               // 1..8 groups of 8 edges
      int g = 0;
      for (; g + 2 <= mg; g += 2) {  // 2 independent 16B loads in flight
        int sA = __builtin_amdgcn_ds_bpermute((((g + 0) << 3) + grp) << 2, sl);
        int sB = __builtin_amdgcn_ds_bpermute((((g + 1) << 3) + grp) << 2, sl);
        v8h rA = *(const v8h*)(xp + (sA << 6) + chOff);
        v8h rB = *(const v8h*)(xp + (sB << 6) + chOff);
        #pragma unroll
        for (int j = 0; j < 8; ++j) {
          accA[j] += (float)rA[j];
          accB[j] += (float)rB[j];
        }
      }
      if (g < mg) {                  // odd tail group
        int sA = __builtin_amdgcn_ds_bpermute(((g << 3) + grp) << 2, sl);
        v8h rA = *(const v8h*)(xp + (sA << 6) + chOff);
        #pragma unroll
        for (int j = 0; j < 8; ++j) accA[j] += (float)rA[j];
      }
    }
    float a[8];
    #pragma unroll
    for (int j = 0; j < 8; ++j) a[j] = accA[j] + accB[j];
    // reduce over the 8 edge-slots (lane bits 3..5)
    #pragma unroll
    for (int j = 0; j < 8; ++j) {
      a[j] += __shfl_xor(a[j], 8);
      a[j] += __shfl_xor(a[j], 16);
      a[j] += __shfl_xor(a[j], 32);
    }
    if (lane < 8) {
      float dv = dinv[vu];
      v8h self = *(const v8h*)(xp + (vu << 6) + chOff);
      v8h o;
      #pragma unroll
      for (int j = 0; j < 8; ++j)
        o[j] = (_Float16)(dv * a[j] + 2.f * dv * (float)self[j]);
      *(v8h*)(sxg + (vu << 6) + chOff) = o;
    }
  }
  }  // rep
}

// ---------------- MFMA cell + readout (one wave per 16-node tile) ----------
__global__ __launch_bounds__(256) void k_cell(
    const _Float16* __restrict__ sxg, const _Float16* __restrict__ Bzh,
    const _Float16* __restrict__ Bwo, const float2* __restrict__ B2,
    const float* __restrict__ bout, float* __restrict__ out) {
  __shared__ __align__(16) _Float16 tbuf[4][16][72];
  int tid = threadIdx.x;
  int lane = tid & 63, wv = tid >> 6;
  int l15 = lane & 15, quad = lane >> 4;
  int tile = blockIdx.x * 4 + wv;
  if (tile >= NTILES) return;    // no barriers in this kernel -> safe

  v8h bzf[8][2], bwf[3][2];
  #pragma unroll
  for (int t = 0; t < 8; ++t)
    #pragma unroll
    for (int ks = 0; ks < 2; ++ks)
      bzf[t][ks] = *(const v8h*)(Bzh + (((t * 2 + ks) * 64 + lane) << 3));
  #pragma unroll
  for (int t = 0; t < 3; ++t)
    #pragma unroll
    for (int ks = 0; ks < 2; ++ks)
      bwf[t][ks] = *(const v8h*)(Bwo + (((t * 2 + ks) * 64 + lane) << 3));
  float zb[4], hb[4], ob[3];
  #pragma unroll
  for (int t = 0; t < 4; ++t) {
    float2 bb = B2[t * 16 + l15];
    zb[t] = bb.x; hb[t] = bb.y;
  }
  #pragma unroll
  for (int t = 0; t < 3; ++t) {
    int c = t * 16 + l15;
    ob[t] = (c < 45) ? bout[c] : 0.f;
  }

  const _Float16* ar = sxg + (tile * 16 + l15) * 64 + quad * 8;
  v8h a0 = *(const v8h*)ar;
  v8h a1 = *(const v8h*)(ar + 32);

  f32x4_t accz[8];
  #pragma unroll
  for (int t = 0; t < 8; ++t) {
    f32x4_t c4 = {0.f, 0.f, 0.f, 0.f};
    c4 = __builtin_amdgcn_mfma_f32_16x16x32_f16(a0, bzf[t][0], c4, 0, 0, 0);
    c4 = __builtin_amdgcn_mfma_f32_16x16x32_f16(a1, bzf[t][1], c4, 0, 0, 0);
    accz[t] = c4;
  }

  #pragma unroll
  for (int t = 0; t < 4; ++t) {
    #pragma unroll
    for (int r = 0; r < 4; ++r) {
      float zv = accz[t][r] + zb[t];
      float hv = accz[t + 4][r] + hb[t];
      float Z = 1.f / (1.f + __expf(-zv));
      float tt = fminf(15.f, fmaxf(-15.f, hv));
      float e2 = __expf(-2.f * tt);
      float Th = (1.f - e2) / (1.f + e2);
      tbuf[wv][quad * 4 + r][t * 16 + l15] = (_Float16)fmaxf((1.f - Z) * Th, 0.f);
    }
  }
  __asm__ volatile("s_waitcnt lgkmcnt(0)" ::: "memory");

  v8h p0 = *(const v8h*)&tbuf[wv][l15][quad * 8];
  v8h p1 = *(const v8h*)&tbuf[wv][l15][32 + quad * 8];

  #pragma unroll
  for (int t = 0; t < 3; ++t) {
    f32x4_t o4 = {0.f, 0.f, 0.f, 0.f};
    o4 = __builtin_amdgcn_mfma_f32_16x16x32_f16(p0, bwf[t][0], o4, 0, 0, 0);
    o4 = __builtin_amdgcn_mfma_f32_16x16x32_f16(p1, bwf[t][1], o4, 0, 0, 0);
    int c = t * 16 + l15;
    if (c < 45) {
      #pragma unroll
      for (int r = 0; r < 4; ++r)
        out[(tile * 16 + quad * 4 + r) * 45 + c] = o4[r] + ob[t];
    }
  }
}

// ---------------- launch ----------------
extern "C" void kernel_launch(void* const* d_in, const int* in_sizes, int n_in,
                              void* d_out, int out_size, void* d_ws, size_t ws_size,
                              hipStream_t stream) {
  const float* x    = (const float*)d_in[0];
  const int*   ei   = (const int*)d_in[1];
  const float* Wz   = (const float*)d_in[2];
  const float* bz   = (const float*)d_in[3];
  const float* Wlz  = (const float*)d_in[4];
  const float* blz  = (const float*)d_in[5];
  // d_in[6..9] (W_r branch) dead: H=0 => H*R=0.
  const float* Wh   = (const float*)d_in[10];
  const float* bh   = (const float*)d_in[11];
  const float* Wlh  = (const float*)d_in[12];
  const float* blh  = (const float*)d_in[13];
  const float* Wout = (const float*)d_in[14];
  const float* bout = (const float*)d_in[15];
  float* out = (float*)d_out;

  char* w = (char*)d_ws;
  // bins (early) and sxg (late) alias: bins dead after k_sort; k_agg never
  // reads bins, so its 3x re-run stays safe under the alias.
  int*      bins  = (int*)(w + 0);            // 782*2560*4 = 8,007,680
  _Float16* sxg   = (_Float16*)(w + 0);       // 6,400,000 (alias)
  int*      gcur  = (int*)(w + 8007680);      // 3,128
  ushort_t* srcp  = (ushort_t*)(w + 8010816); // 782*3072*2 = 4,804,608
  int2*     rowiv = (int2*)(w + 12815424);    // 400,000
  float*    dinv  = (float*)(w + 13215424);   // 200,000
  float2*   B2    = (float2*)(w + 13415424);  // 512
  _Float16* Bzh   = (_Float16*)(w + 13415936);// 16,384
  _Float16* Bwo   = (_Float16*)(w + 13432320);// 6,144
  _Float16* xp    = (_Float16*)(w + 13438464);// 6,400,128 -> ends ~19.8 MB

  hipMemsetAsync(gcur, 0, NB * sizeof(int), stream);
  k_binw <<<NBB + 8, 256, 0, stream>>>(ei, gcur, bins, Wz, bz, Wlz, blz,
                                       Wh, bh, Wlh, blh, Wout,
                                       (float*)B2, Bzh, Bwo);
  k_sort <<<NB, 256, 0, stream>>>(bins, gcur, x, srcp, rowiv, dinv, xp);
  k_agg  <<<2048, 256, 0, stream>>>(srcp, rowiv, dinv, xp, sxg);
  k_cell <<<NB, 256, 0, stream>>>(sxg, Bzh, Bwo, B2, bout, out);
}

// Round 8
// 184.744 us; speedup vs baseline: 1.0687x; 1.0687x over previous
//
#include <hip/hip_runtime.h>

#define N_NODES 50000
#define N_EDGES 1600000
#define NB 782            // buckets of 64 dst nodes: ceil(50000/64)
#define NBB 256           // binning blocks
#define CHUNK 6250        // N_EDGES / NBB (exact, even)
#define CAP 2560          // fixed bucket capacity (mean 2046 + 11 sigma)
#define SCAP 3072         // srcp per-bucket capacity (CAP + pad slack)
#define ZROW 50000        // dummy src row (all zeros) for padding
#define NTILES 3125       // 50000 / 16 exact

typedef unsigned short ushort_t;
typedef _Float16 v8h __attribute__((ext_vector_type(8)));
typedef _Float16 v4h __attribute__((ext_vector_type(4)));
typedef float f32x4_t __attribute__((ext_vector_type(4)));

// r8: split-pass gather. xp stored as two 32-channel halves (3.2 MB each,
// fits per-XCD 4MB L2); k_agg runs once per half.  r7 PMC showed k_agg
// FETCH 47MB/rep (xp 6.4MB re-fetched ~7x from L3) at ~10 TB/s effective.

// ========== fused binning + weight prep (independent block families) ======
__global__ __launch_bounds__(256) void k_binw(
    const int* __restrict__ ei, int* __restrict__ gcur, int* __restrict__ bins,
    const float* __restrict__ Wz, const float* __restrict__ bz,
    const float* __restrict__ Wlz, const float* __restrict__ blz,
    const float* __restrict__ Wh, const float* __restrict__ bh,
    const float* __restrict__ Wlh, const float* __restrict__ blh,
    const float* __restrict__ Wout, float* __restrict__ B2f,
    _Float16* __restrict__ Bzh, _Float16* __restrict__ Bwo) {
  __shared__ int arena[8320];   // bin: 2*NB+CHUNK=7814 ints; wprep: 8320 floats
  int tid = threadIdx.x, blk = blockIdx.x;
  if (blk < NBB) {
    int* h    = arena;          // 782
    int* segb = arena + NB;     // 782
    int* pk   = arena + 2 * NB; // 6250
    for (int i = tid; i < NB; i += 256) h[i] = 0;
    __syncthreads();
    const int2* s2 = (const int2*)(ei + blk * CHUNK);
    const int2* d2 = (const int2*)(ei + N_EDGES + blk * CHUNK);
    for (int i = tid; i < CHUNK / 2; i += 256) {
      int2 s = s2[i];
      int2 d = d2[i];
      pk[2 * i]     = s.x | ((d.x & 63) << 16) | ((d.x >> 6) << 22);
      pk[2 * i + 1] = s.y | ((d.y & 63) << 16) | ((d.y >> 6) << 22);
      atomicAdd(&h[d.x >> 6], 1);
      atomicAdd(&h[d.y >> 6], 1);
    }
    __syncthreads();
    for (int b = tid; b < NB; b += 256) {
      int c = h[b];
      segb[b] = c ? atomicAdd(&gcur[b], c) : 0;
      h[b] = 0;                       // reuse as local cursor
    }
    __syncthreads();
    for (int i = tid; i < CHUNK; i += 256) {
      int v = pk[i];
      int b = (unsigned)v >> 22;
      int p = atomicAdd(&h[b], 1);
      bins[b * CAP + segb[b] + p] = v & 0x3FFFFF;   // src | dl<<16
    }
  } else {
    // weight prep: wblk 0-3 z-path, 4-7 h-path; ntile = wblk&3
    int wblk = blk - NBB;
    float* A  = (float*)arena;           // 64x65
    float* Bm = (float*)(arena + 4160);  // 64x65
    bool zpath = wblk < 4;
    const float* Wsrc = zpath ? Wz : Wh;
    const float* Lsrc = zpath ? Wlz : Wlh;
    for (int idx = tid; idx < 4096; idx += 256) {
      A[(idx >> 6) * 65 + (idx & 63)] = Wsrc[idx];
      Bm[(idx >> 6) * 65 + (idx & 63)] = Lsrc[idx];
    }
    __syncthreads();
    int lane = (tid >> 1) & 63;
    int j0 = (tid & 1) * 4;
    int ks = (tid >> 7) & 1;
    int k0 = ks * 32 + ((lane >> 4) << 3) + j0;
    int col = (wblk & 3) * 16 + (lane & 15);
    float a0 = 0.f, a1 = 0.f, a2 = 0.f, a3 = 0.f;
    for (int q = 0; q < 64; ++q) {
      float bv = Bm[q * 65 + col];
      a0 = fmaf(A[k0 * 65 + q], bv, a0);
      a1 = fmaf(A[(k0 + 1) * 65 + q], bv, a1);
      a2 = fmaf(A[(k0 + 2) * 65 + q], bv, a2);
      a3 = fmaf(A[(k0 + 3) * 65 + q], bv, a3);
    }
    int tb = wblk * 1024 + tid * 4;
    v4h o; o[0] = (_Float16)a0; o[1] = (_Float16)a1;
    o[2] = (_Float16)a2; o[3] = (_Float16)a3;
    *(v4h*)(Bzh + tb) = o;
    if ((wblk == 0 || wblk == 4) && tid < 64) {
      float v = zpath ? blz[tid] : blh[tid];
      const float* bb = zpath ? bz : bh;
      for (int q = 0; q < 64; ++q) v = fmaf(bb[q], Bm[q * 65 + tid], v);
      B2f[tid * 2 + (zpath ? 0 : 1)] = v;
    }
    if (wblk == 1) {
      for (int e2 = 0; e2 < 12; ++e2) {
        int t2 = tid * 12 + e2;
        int ln = (t2 >> 3) & 63, j = t2 & 7;
        int ntile = t2 >> 10, ks2 = (t2 >> 9) & 1;
        int n = ntile * 16 + (ln & 15);
        int k = ks2 * 32 + ((ln >> 4) << 3) + j;
        Bwo[t2] = (_Float16)((n < 45) ? Wout[k * 45 + n] : 0.f);
      }
    }
  }
}

// ------ per-bucket sort -> padded per-node CSR + dinv + xpL/xpH halves -----
__global__ __launch_bounds__(256, 4) void k_sort(
    const int* __restrict__ bins, const int* __restrict__ gcur,
    const float* __restrict__ x,
    ushort_t* __restrict__ srcp, int2* __restrict__ rowiv,
    float* __restrict__ dinv, _Float16* __restrict__ xpL,
    _Float16* __restrict__ xpH) {
  __shared__ int dg[64], lo[64], cur[64];
  __shared__ float sdin[64];
  __shared__ int Tsh;
  __shared__ ushort_t buf[8192];
  int tid = threadIdx.x, b = blockIdx.x;
  int start = b * CAP, end = start + gcur[b];
  if (tid < 64) dg[tid] = 0;
  __syncthreads();
  for (int i = start + tid; i < end; i += 256)
    atomicAdd(&dg[bins[i] >> 16], 1);
  __syncthreads();
  int pdv = 0;
  if (tid < 64) { pdv = (dg[tid] + 7) & ~7; lo[tid] = pdv; }
  __syncthreads();
  for (int off = 1; off < 64; off <<= 1) {
    int u = 0;
    if (tid < 64 && tid >= off) u = lo[tid - off];
    __syncthreads();
    if (tid < 64) lo[tid] += u;
    __syncthreads();
  }
  int ex = 0;
  if (tid < 64) {
    ex = lo[tid] - pdv;       // exclusive padded offset
    cur[tid] = ex;
    if (tid == 63) Tsh = lo[63];
  }
  __syncthreads();
  int T = Tsh;
  int base = b * SCAP;        // fixed per-bucket srcp region
  for (int i = tid; i < T; i += 256) buf[i] = (ushort_t)ZROW;
  __syncthreads();
  for (int i = start + tid; i < end; i += 256) {
    int v = bins[i];
    int dl = v >> 16;
    int p = atomicAdd(&cur[dl], 1);
    buf[p] = (ushort_t)(v & 0xFFFF);
  }
  __syncthreads();
  for (int i = tid; i < T; i += 256) srcp[base + i] = buf[i];
  if (tid < 64) {
    int v = b * 64 + tid;
    if (v < N_NODES) {
      rowiv[v] = make_int2(base + ex, pdv);
      float dv = rsqrtf((float)dg[tid] + 2.0f);
      dinv[v] = dv;
      sdin[tid] = dv;
    } else {
      sdin[tid] = 0.f;
    }
  }
  __syncthreads();
  // vectorized x -> xpL/xpH (float4 in, v4h out into the matching half)
  const float4* x4 = (const float4*)x;
  int base4 = b * 1024;           // float4 index of bucket start
  for (int idx = tid; idx < 1024; idx += 256) {
    int row = idx >> 4;           // 16 float4 per 64-ch row
    int c4 = idx & 15;            // channels c4*4 .. +3
    int v = b * 64 + row;
    if (v < N_NODES) {
      float4 xv = x4[base4 + idx];
      float s = sdin[row];
      v4h o;
      o[0] = (_Float16)(s * xv.x); o[1] = (_Float16)(s * xv.y);
      o[2] = (_Float16)(s * xv.z); o[3] = (_Float16)(s * xv.w);
      if (c4 < 8) *(v4h*)(xpL + (v << 5) + (c4 << 2)) = o;
      else        *(v4h*)(xpH + (v << 5) + ((c4 - 8) << 2)) = o;
    }
  }
  if (b == 0 && tid < 32) {
    xpL[(ZROW << 5) + tid] = (_Float16)0.f;
    xpH[(ZROW << 5) + tid] = (_Float16)0.f;
  }
}

// ---- gather (one 32-ch half): 4 lanes x 16B per edge, 16 edge slots -------
// Working set per pass = one 3.2MB half -> L2-resident on every XCD.
// ZROW-padded slots read the zero row, so no masking beyond lane<m needed.
__global__ __launch_bounds__(256, 8) void k_agg(
    const ushort_t* __restrict__ srcp, const int2* __restrict__ rowiv,
    const float* __restrict__ dinv, const _Float16* __restrict__ xpA,
    _Float16* __restrict__ sxg, int cb) {
  int tid = threadIdx.x;
  int lane = tid & 63;
  int grp = lane >> 2;          // edge slot 0..15
  int chOff = (lane & 3) << 3;  // channels (lane&3)*8 .. +7 within the half
  int w = blockIdx.x * 4 + (tid >> 6);
  int nw = gridDim.x * 4;
  for (int v = w; v < N_NODES; v += nw) {
    int vu = __builtin_amdgcn_readfirstlane(v);
    int2 ri = rowiv[vu];
    int beg = ri.x, pd = ri.y;    // pd multiple of 8
    float accA[8], accB[8];
    #pragma unroll
    for (int j = 0; j < 8; ++j) { accA[j] = 0.f; accB[j] = 0.f; }
    for (int e = beg; e < beg + pd; e += 64) {
      int rem = beg + pd - e;
      int m = rem < 64 ? rem : 64;   // multiple of 8
      int sl = (lane < m) ? (int)srcp[e + lane] : ZROW;
      int ng = (m + 15) >> 4;        // 16-edge groups (ZROW pads partials)
      int g = 0;
      for (; g + 2 <= ng; g += 2) {  // 2 independent 16B loads in flight
        int sA = __builtin_amdgcn_ds_bpermute((((g + 0) << 4) + grp) << 2, sl);
        int sB = __builtin_amdgcn_ds_bpermute((((g + 1) << 4) + grp) << 2, sl);
        v8h rA = *(const v8h*)(xpA + (sA << 5) + chOff);
        v8h rB = *(const v8h*)(xpA + (sB << 5) + chOff);
        #pragma unroll
        for (int j = 0; j < 8; ++j) {
          accA[j] += (float)rA[j];
          accB[j] += (float)rB[j];
        }
      }
      if (g < ng) {                  // odd tail group
        int sA = __builtin_amdgcn_ds_bpermute(((g << 4) + grp) << 2, sl);
        v8h rA = *(const v8h*)(xpA + (sA << 5) + chOff);
        #pragma unroll
        for (int j = 0; j < 8; ++j) accA[j] += (float)rA[j];
      }
    }
    float a[8];
    #pragma unroll
    for (int j = 0; j < 8; ++j) a[j] = accA[j] + accB[j];
    // reduce over the 16 edge-slots (lane bits 2..5)
    #pragma unroll
    for (int j = 0; j < 8; ++j) {
      a[j] += __shfl_xor(a[j], 4);
      a[j] += __shfl_xor(a[j], 8);
      a[j] += __shfl_xor(a[j], 16);
      a[j] += __shfl_xor(a[j], 32);
    }
    if (lane < 4) {
      float dv = dinv[vu];
      v8h self = *(const v8h*)(xpA + (vu << 5) + chOff);
      v8h o;
      #pragma unroll
      for (int j = 0; j < 8; ++j)
        o[j] = (_Float16)(dv * a[j] + 2.f * dv * (float)self[j]);
      *(v8h*)(sxg + (vu << 6) + cb + chOff) = o;
    }
  }
}

// ---------------- MFMA cell + readout (one wave per 16-node tile) ----------
__global__ __launch_bounds__(256) void k_cell(
    const _Float16* __restrict__ sxg, const _Float16* __restrict__ Bzh,
    const _Float16* __restrict__ Bwo, const float2* __restrict__ B2,
    const float* __restrict__ bout, float* __restrict__ out) {
  __shared__ __align__(16) _Float16 tbuf[4][16][72];
  int tid = threadIdx.x;
  int lane = tid & 63, wv = tid >> 6;
  int l15 = lane & 15, quad = lane >> 4;
  int tile = blockIdx.x * 4 + wv;
  if (tile >= NTILES) return;    // no barriers in this kernel -> safe

  v8h bzf[8][2], bwf[3][2];
  #pragma unroll
  for (int t = 0; t < 8; ++t)
    #pragma unroll
    for (int ks = 0; ks < 2; ++ks)
      bzf[t][ks] = *(const v8h*)(Bzh + (((t * 2 + ks) * 64 + lane) << 3));
  #pragma unroll
  for (int t = 0; t < 3; ++t)
    #pragma unroll
    for (int ks = 0; ks < 2; ++ks)
      bwf[t][ks] = *(const v8h*)(Bwo + (((t * 2 + ks) * 64 + lane) << 3));
  float zb[4], hb[4], ob[3];
  #pragma unroll
  for (int t = 0; t < 4; ++t) {
    float2 bb = B2[t * 16 + l15];
    zb[t] = bb.x; hb[t] = bb.y;
  }
  #pragma unroll
  for (int t = 0; t < 3; ++t) {
    int c = t * 16 + l15;
    ob[t] = (c < 45) ? bout[c] : 0.f;
  }

  const _Float16* ar = sxg + (tile * 16 + l15) * 64 + quad * 8;
  v8h a0 = *(const v8h*)ar;
  v8h a1 = *(const v8h*)(ar + 32);

  f32x4_t accz[8];
  #pragma unroll
  for (int t = 0; t < 8; ++t) {
    f32x4_t c4 = {0.f, 0.f, 0.f, 0.f};
    c4 = __builtin_amdgcn_mfma_f32_16x16x32_f16(a0, bzf[t][0], c4, 0, 0, 0);
    c4 = __builtin_amdgcn_mfma_f32_16x16x32_f16(a1, bzf[t][1], c4, 0, 0, 0);
    accz[t] = c4;
  }

  #pragma unroll
  for (int t = 0; t < 4; ++t) {
    #pragma unroll
    for (int r = 0; r < 4; ++r) {
      float zv = accz[t][r] + zb[t];
      float hv = accz[t + 4][r] + hb[t];
      float Z = 1.f / (1.f + __expf(-zv));
      float tt = fminf(15.f, fmaxf(-15.f, hv));
      float e2 = __expf(-2.f * tt);
      float Th = (1.f - e2) / (1.f + e2);
      tbuf[wv][quad * 4 + r][t * 16 + l15] = (_Float16)fmaxf((1.f - Z) * Th, 0.f);
    }
  }
  __asm__ volatile("s_waitcnt lgkmcnt(0)" ::: "memory");

  v8h p0 = *(const v8h*)&tbuf[wv][l15][quad * 8];
  v8h p1 = *(const v8h*)&tbuf[wv][l15][32 + quad * 8];

  #pragma unroll
  for (int t = 0; t < 3; ++t) {
    f32x4_t o4 = {0.f, 0.f, 0.f, 0.f};
    o4 = __builtin_amdgcn_mfma_f32_16x16x32_f16(p0, bwf[t][0], o4, 0, 0, 0);
    o4 = __builtin_amdgcn_mfma_f32_16x16x32_f16(p1, bwf[t][1], o4, 0, 0, 0);
    int c = t * 16 + l15;
    if (c < 45) {
      #pragma unroll
      for (int r = 0; r < 4; ++r)
        out[(tile * 16 + quad * 4 + r) * 45 + c] = o4[r] + ob[t];
    }
  }
}

// ---------------- launch ----------------
extern "C" void kernel_launch(void* const* d_in, const int* in_sizes, int n_in,
                              void* d_out, int out_size, void* d_ws, size_t ws_size,
                              hipStream_t stream) {
  const float* x    = (const float*)d_in[0];
  const int*   ei   = (const int*)d_in[1];
  const float* Wz   = (const float*)d_in[2];
  const float* bz   = (const float*)d_in[3];
  const float* Wlz  = (const float*)d_in[4];
  const float* blz  = (const float*)d_in[5];
  // d_in[6..9] (W_r branch) dead: H=0 => H*R=0.
  const float* Wh   = (const float*)d_in[10];
  const float* bh   = (const float*)d_in[11];
  const float* Wlh  = (const float*)d_in[12];
  const float* blh  = (const float*)d_in[13];
  const float* Wout = (const float*)d_in[14];
  const float* bout = (const float*)d_in[15];
  float* out = (float*)d_out;

  char* w = (char*)d_ws;
  // bins (early) and sxg (late) alias: bins dead after k_sort.
  int*      bins  = (int*)(w + 0);            // 782*2560*4 = 8,007,680
  _Float16* sxg   = (_Float16*)(w + 0);       // 6,400,000 (alias)
  int*      gcur  = (int*)(w + 8007680);      // 3,128
  ushort_t* srcp  = (ushort_t*)(w + 8010816); // 782*3072*2 = 4,804,608
  int2*     rowiv = (int2*)(w + 12815424);    // 400,000
  float*    dinv  = (float*)(w + 13215424);   // 200,000
  float2*   B2    = (float2*)(w + 13415424);  // 512
  _Float16* Bzh   = (_Float16*)(w + 13415936);// 16,384
  _Float16* Bwo   = (_Float16*)(w + 13432320);// 6,144
  _Float16* xpL   = (_Float16*)(w + 13438464);// 50001*64B = 3,200,128
  _Float16* xpH   = (_Float16*)(w + 16638592);// 3,200,128 -> ends ~19.8 MB

  hipMemsetAsync(gcur, 0, NB * sizeof(int), stream);
  k_binw <<<NBB + 8, 256, 0, stream>>>(ei, gcur, bins, Wz, bz, Wlz, blz,
                                       Wh, bh, Wlh, blh, Wout,
                                       (float*)B2, Bzh, Bwo);
  k_sort <<<NB, 256, 0, stream>>>(bins, gcur, x, srcp, rowiv, dinv, xpL, xpH);
  k_agg  <<<2048, 256, 0, stream>>>(srcp, rowiv, dinv, xpL, sxg, 0);
  k_agg  <<<2048, 256, 0, stream>>>(srcp, rowiv, dinv, xpH, sxg, 32);
  k_cell <<<NB, 256, 0, stream>>>(sxg, Bzh, Bwo, B2, bout, out);
}

// Round 9
// 159.547 us; speedup vs baseline: 1.2374x; 1.1579x over previous
//
#include <hip/hip_runtime.h>

#define N_NODES 50000
#define N_EDGES 1600000
#define NB 782            // buckets of 64 dst nodes: ceil(50000/64)
#define NBB 256           // binning blocks
#define CHUNK 6250        // N_EDGES / NBB (exact, even)
#define CAP 2560          // fixed bucket capacity (mean 2046 + 11 sigma)
#define SCAP 3072         // srcp per-bucket capacity (CAP + pad slack)
#define ZROW 50000        // dummy src row (all zeros) for padding
#define NTILES 3125       // 50000 / 16 exact

typedef unsigned short ushort_t;
typedef _Float16 v8h __attribute__((ext_vector_type(8)));
typedef _Float16 v4h __attribute__((ext_vector_type(4)));
typedef _Float16 v2h __attribute__((ext_vector_type(2)));
typedef float f32x4_t __attribute__((ext_vector_type(4)));

// r9: revert r8's split-pass (regressed: xp was already L2-resident per XCD,
// FETCH 47MB = 8 XCD x 6.4MB replication).  Attack k_agg's VALU instead:
// v_dot2_f32_f16 (fdot2 with (1,0)/(0,1)) = 1 VALU/channel vs cvt+add's 2,
// identical numerics; 4-deep load pipeline to cover L2 latency.

// ========== fused binning + weight prep (independent block families) ======
__global__ __launch_bounds__(256) void k_binw(
    const int* __restrict__ ei, int* __restrict__ gcur, int* __restrict__ bins,
    const float* __restrict__ Wz, const float* __restrict__ bz,
    const float* __restrict__ Wlz, const float* __restrict__ blz,
    const float* __restrict__ Wh, const float* __restrict__ bh,
    const float* __restrict__ Wlh, const float* __restrict__ blh,
    const float* __restrict__ Wout, float* __restrict__ B2f,
    _Float16* __restrict__ Bzh, _Float16* __restrict__ Bwo) {
  __shared__ int arena[8320];   // bin: 2*NB+CHUNK=7814 ints; wprep: 8320 floats
  int tid = threadIdx.x, blk = blockIdx.x;
  if (blk < NBB) {
    int* h    = arena;          // 782
    int* segb = arena + NB;     // 782
    int* pk   = arena + 2 * NB; // 6250
    for (int i = tid; i < NB; i += 256) h[i] = 0;
    __syncthreads();
    const int2* s2 = (const int2*)(ei + blk * CHUNK);
    const int2* d2 = (const int2*)(ei + N_EDGES + blk * CHUNK);
    for (int i = tid; i < CHUNK / 2; i += 256) {
      int2 s = s2[i];
      int2 d = d2[i];
      pk[2 * i]     = s.x | ((d.x & 63) << 16) | ((d.x >> 6) << 22);
      pk[2 * i + 1] = s.y | ((d.y & 63) << 16) | ((d.y >> 6) << 22);
      atomicAdd(&h[d.x >> 6], 1);
      atomicAdd(&h[d.y >> 6], 1);
    }
    __syncthreads();
    for (int b = tid; b < NB; b += 256) {
      int c = h[b];
      segb[b] = c ? atomicAdd(&gcur[b], c) : 0;
      h[b] = 0;                       // reuse as local cursor
    }
    __syncthreads();
    for (int i = tid; i < CHUNK; i += 256) {
      int v = pk[i];
      int b = (unsigned)v >> 22;
      int p = atomicAdd(&h[b], 1);
      bins[b * CAP + segb[b] + p] = v & 0x3FFFFF;   // src | dl<<16
    }
  } else {
    // weight prep: wblk 0-3 z-path, 4-7 h-path; ntile = wblk&3
    int wblk = blk - NBB;
    float* A  = (float*)arena;           // 64x65
    float* Bm = (float*)(arena + 4160);  // 64x65
    bool zpath = wblk < 4;
    const float* Wsrc = zpath ? Wz : Wh;
    const float* Lsrc = zpath ? Wlz : Wlh;
    for (int idx = tid; idx < 4096; idx += 256) {
      A[(idx >> 6) * 65 + (idx & 63)] = Wsrc[idx];
      Bm[(idx >> 6) * 65 + (idx & 63)] = Lsrc[idx];
    }
    __syncthreads();
    int lane = (tid >> 1) & 63;
    int j0 = (tid & 1) * 4;
    int ks = (tid >> 7) & 1;
    int k0 = ks * 32 + ((lane >> 4) << 3) + j0;
    int col = (wblk & 3) * 16 + (lane & 15);
    float a0 = 0.f, a1 = 0.f, a2 = 0.f, a3 = 0.f;
    for (int q = 0; q < 64; ++q) {
      float bv = Bm[q * 65 + col];
      a0 = fmaf(A[k0 * 65 + q], bv, a0);
      a1 = fmaf(A[(k0 + 1) * 65 + q], bv, a1);
      a2 = fmaf(A[(k0 + 2) * 65 + q], bv, a2);
      a3 = fmaf(A[(k0 + 3) * 65 + q], bv, a3);
    }
    int tb = wblk * 1024 + tid * 4;
    v4h o; o[0] = (_Float16)a0; o[1] = (_Float16)a1;
    o[2] = (_Float16)a2; o[3] = (_Float16)a3;
    *(v4h*)(Bzh + tb) = o;
    if ((wblk == 0 || wblk == 4) && tid < 64) {
      float v = zpath ? blz[tid] : blh[tid];
      const float* bb = zpath ? bz : bh;
      for (int q = 0; q < 64; ++q) v = fmaf(bb[q], Bm[q * 65 + tid], v);
      B2f[tid * 2 + (zpath ? 0 : 1)] = v;
    }
    if (wblk == 1) {
      for (int e2 = 0; e2 < 12; ++e2) {
        int t2 = tid * 12 + e2;
        int ln = (t2 >> 3) & 63, j = t2 & 7;
        int ntile = t2 >> 10, ks2 = (t2 >> 9) & 1;
        int n = ntile * 16 + (ln & 15);
        int k = ks2 * 32 + ((ln >> 4) << 3) + j;
        Bwo[t2] = (_Float16)((n < 45) ? Wout[k * 45 + n] : 0.f);
      }
    }
  }
}

// ---------------- per-bucket sort -> padded per-node CSR + dinv + xp -------
__global__ __launch_bounds__(256, 4) void k_sort(
    const int* __restrict__ bins, const int* __restrict__ gcur,
    const float* __restrict__ x,
    ushort_t* __restrict__ srcp, int2* __restrict__ rowiv,
    float* __restrict__ dinv, _Float16* __restrict__ xp) {
  __shared__ int dg[64], lo[64], cur[64];
  __shared__ float sdin[64];
  __shared__ int Tsh;
  __shared__ ushort_t buf[8192];
  int tid = threadIdx.x, b = blockIdx.x;
  int start = b * CAP, end = start + gcur[b];
  if (tid < 64) dg[tid] = 0;
  __syncthreads();
  for (int i = start + tid; i < end; i += 256)
    atomicAdd(&dg[bins[i] >> 16], 1);
  __syncthreads();
  int pdv = 0;
  if (tid < 64) { pdv = (dg[tid] + 7) & ~7; lo[tid] = pdv; }
  __syncthreads();
  for (int off = 1; off < 64; off <<= 1) {
    int u = 0;
    if (tid < 64 && tid >= off) u = lo[tid - off];
    __syncthreads();
    if (tid < 64) lo[tid] += u;
    __syncthreads();
  }
  int ex = 0;
  if (tid < 64) {
    ex = lo[tid] - pdv;       // exclusive padded offset
    cur[tid] = ex;
    if (tid == 63) Tsh = lo[63];
  }
  __syncthreads();
  int T = Tsh;
  int base = b * SCAP;        // fixed per-bucket srcp region
  for (int i = tid; i < T; i += 256) buf[i] = (ushort_t)ZROW;
  __syncthreads();
  for (int i = start + tid; i < end; i += 256) {
    int v = bins[i];
    int dl = v >> 16;
    int p = atomicAdd(&cur[dl], 1);
    buf[p] = (ushort_t)(v & 0xFFFF);
  }
  __syncthreads();
  for (int i = tid; i < T; i += 256) srcp[base + i] = buf[i];
  if (tid < 64) {
    int v = b * 64 + tid;
    if (v < N_NODES) {
      rowiv[v] = make_int2(base + ex, pdv);
      float dv = rsqrtf((float)dg[tid] + 2.0f);
      dinv[v] = dv;
      sdin[tid] = dv;
    } else {
      sdin[tid] = 0.f;
    }
  }
  __syncthreads();
  // vectorized x -> xp (float4 in, v4h out)
  const float4* x4 = (const float4*)x;
  int base4 = b * 1024;           // float4 index of bucket start
  int nb64 = b * 4096;            // half index of bucket start
  for (int idx = tid; idx < 1024; idx += 256) {
    int row = idx >> 4;           // 16 float4 per 64-ch row
    int v = b * 64 + row;
    if (v < N_NODES) {
      float4 xv = x4[base4 + idx];
      float s = sdin[row];
      v4h o;
      o[0] = (_Float16)(s * xv.x); o[1] = (_Float16)(s * xv.y);
      o[2] = (_Float16)(s * xv.z); o[3] = (_Float16)(s * xv.w);
      *(v4h*)(xp + nb64 + idx * 4) = o;
    }
  }
  if (b == 0 && tid < 64) xp[ZROW * 64 + tid] = (_Float16)0.f;
}

// ------- gather: 8 lanes x 16B per edge, fdot2 accumulate, 4-deep ----------
// Per v8h load: 8 fdot2 (1 VALU/channel, exact f32 accumulate) vs 16 cvt+add.
// 4 bpermute+load pairs in flight, alternating into 2 accumulator sets.
__global__ __launch_bounds__(256, 8) void k_agg(
    const ushort_t* __restrict__ srcp, const int2* __restrict__ rowiv,
    const float* __restrict__ dinv, const _Float16* __restrict__ xp,
    _Float16* __restrict__ sxg) {
  int tid = threadIdx.x;
  int lane = tid & 63;
  int grp = lane >> 3;          // edge slot 0..7 within a group of 8
  int chOff = (lane & 7) << 3;  // channels (lane&7)*8 .. +7
  const v2h onE = {(_Float16)1.0f, (_Float16)0.0f};
  const v2h onO = {(_Float16)0.0f, (_Float16)1.0f};
  int w = blockIdx.x * 4 + (tid >> 6);
  int nw = gridDim.x * 4;
  for (int v = w; v < N_NODES; v += nw) {
    int vu = __builtin_amdgcn_readfirstlane(v);
    int2 ri = rowiv[vu];
    int beg = ri.x, pd = ri.y;    // pd multiple of 8
    float aE[2][4], aO[2][4];     // [slot][pair]: even/odd channel of pair j
    #pragma unroll
    for (int j = 0; j < 4; ++j) {
      aE[0][j] = 0.f; aE[1][j] = 0.f; aO[0][j] = 0.f; aO[1][j] = 0.f;
    }
    for (int e = beg; e < beg + pd; e += 64) {
      int rem = beg + pd - e;
      int m = rem < 64 ? rem : 64;   // multiple of 8
      int sl = (lane < m) ? (int)srcp[e + lane] : ZROW;
      int mg = m >> 3;               // 1..8 groups of 8 edges
      int g = 0;
      for (; g + 4 <= mg; g += 4) {  // 4 independent 16B loads in flight
        int s0 = __builtin_amdgcn_ds_bpermute((((g + 0) << 3) + grp) << 2, sl);
        int s1 = __builtin_amdgcn_ds_bpermute((((g + 1) << 3) + grp) << 2, sl);
        int s2 = __builtin_amdgcn_ds_bpermute((((g + 2) << 3) + grp) << 2, sl);
        int s3 = __builtin_amdgcn_ds_bpermute((((g + 3) << 3) + grp) << 2, sl);
        v8h r0 = *(const v8h*)(xp + (s0 << 6) + chOff);
        v8h r1 = *(const v8h*)(xp + (s1 << 6) + chOff);
        v8h r2 = *(const v8h*)(xp + (s2 << 6) + chOff);
        v8h r3 = *(const v8h*)(xp + (s3 << 6) + chOff);
        const v2h* p0 = (const v2h*)&r0;
        const v2h* p1 = (const v2h*)&r1;
        const v2h* p2 = (const v2h*)&r2;
        const v2h* p3 = (const v2h*)&r3;
        #pragma unroll
        for (int j = 0; j < 4; ++j) {
          aE[0][j] = __builtin_amdgcn_fdot2(p0[j], onE, aE[0][j], false);
          aO[0][j] = __builtin_amdgcn_fdot2(p0[j], onO, aO[0][j], false);
          aE[1][j] = __builtin_amdgcn_fdot2(p1[j], onE, aE[1][j], false);
          aO[1][j] = __builtin_amdgcn_fdot2(p1[j], onO, aO[1][j], false);
          aE[0][j] = __builtin_amdgcn_fdot2(p2[j], onE, aE[0][j], false);
          aO[0][j] = __builtin_amdgcn_fdot2(p2[j], onO, aO[0][j], false);
          aE[1][j] = __builtin_amdgcn_fdot2(p3[j], onE, aE[1][j], false);
          aO[1][j] = __builtin_amdgcn_fdot2(p3[j], onO, aO[1][j], false);
        }
      }
      for (; g < mg; ++g) {          // 0-3 tail groups
        int s0 = __builtin_amdgcn_ds_bpermute(((g << 3) + grp) << 2, sl);
        v8h r0 = *(const v8h*)(xp + (s0 << 6) + chOff);
        const v2h* p0 = (const v2h*)&r0;
        #pragma unroll
        for (int j = 0; j < 4; ++j) {
          aE[0][j] = __builtin_amdgcn_fdot2(p0[j], onE, aE[0][j], false);
          aO[0][j] = __builtin_amdgcn_fdot2(p0[j], onO, aO[0][j], false);
        }
      }
    }
    float a[8];
    #pragma unroll
    for (int j = 0; j < 4; ++j) {
      a[2 * j]     = aE[0][j] + aE[1][j];
      a[2 * j + 1] = aO[0][j] + aO[1][j];
    }
    // reduce over the 8 edge-slots (lane bits 3..5)
    #pragma unroll
    for (int j = 0; j < 8; ++j) {
      a[j] += __shfl_xor(a[j], 8);
      a[j] += __shfl_xor(a[j], 16);
      a[j] += __shfl_xor(a[j], 32);
    }
    if (lane < 8) {
      float dv = dinv[vu];
      v8h self = *(const v8h*)(xp + (vu << 6) + chOff);
      v8h o;
      #pragma unroll
      for (int j = 0; j < 8; ++j)
        o[j] = (_Float16)(dv * a[j] + 2.f * dv * (float)self[j]);
      *(v8h*)(sxg + (vu << 6) + chOff) = o;
    }
  }
}

// ---------------- MFMA cell + readout (one wave per 16-node tile) ----------
__global__ __launch_bounds__(256) void k_cell(
    const _Float16* __restrict__ sxg, const _Float16* __restrict__ Bzh,
    const _Float16* __restrict__ Bwo, const float2* __restrict__ B2,
    const float* __restrict__ bout, float* __restrict__ out) {
  __shared__ __align__(16) _Float16 tbuf[4][16][72];
  int tid = threadIdx.x;
  int lane = tid & 63, wv = tid >> 6;
  int l15 = lane & 15, quad = lane >> 4;
  int tile = blockIdx.x * 4 + wv;
  if (tile >= NTILES) return;    // no barriers in this kernel -> safe

  v8h bzf[8][2], bwf[3][2];
  #pragma unroll
  for (int t = 0; t < 8; ++t)
    #pragma unroll
    for (int ks = 0; ks < 2; ++ks)
      bzf[t][ks] = *(const v8h*)(Bzh + (((t * 2 + ks) * 64 + lane) << 3));
  #pragma unroll
  for (int t = 0; t < 3; ++t)
    #pragma unroll
    for (int ks = 0; ks < 2; ++ks)
      bwf[t][ks] = *(const v8h*)(Bwo + (((t * 2 + ks) * 64 + lane) << 3));
  float zb[4], hb[4], ob[3];
  #pragma unroll
  for (int t = 0; t < 4; ++t) {
    float2 bb = B2[t * 16 + l15];
    zb[t] = bb.x; hb[t] = bb.y;
  }
  #pragma unroll
  for (int t = 0; t < 3; ++t) {
    int c = t * 16 + l15;
    ob[t] = (c < 45) ? bout[c] : 0.f;
  }

  const _Float16* ar = sxg + (tile * 16 + l15) * 64 + quad * 8;
  v8h a0 = *(const v8h*)ar;
  v8h a1 = *(const v8h*)(ar + 32);

  f32x4_t accz[8];
  #pragma unroll
  for (int t = 0; t < 8; ++t) {
    f32x4_t c4 = {0.f, 0.f, 0.f, 0.f};
    c4 = __builtin_amdgcn_mfma_f32_16x16x32_f16(a0, bzf[t][0], c4, 0, 0, 0);
    c4 = __builtin_amdgcn_mfma_f32_16x16x32_f16(a1, bzf[t][1], c4, 0, 0, 0);
    accz[t] = c4;
  }

  #pragma unroll
  for (int t = 0; t < 4; ++t) {
    #pragma unroll
    for (int r = 0; r < 4; ++r) {
      float zv = accz[t][r] + zb[t];
      float hv = accz[t + 4][r] + hb[t];
      float Z = 1.f / (1.f + __expf(-zv));
      float tt = fminf(15.f, fmaxf(-15.f, hv));
      float e2 = __expf(-2.f * tt);
      float Th = (1.f - e2) / (1.f + e2);
      tbuf[wv][quad * 4 + r][t * 16 + l15] = (_Float16)fmaxf((1.f - Z) * Th, 0.f);
    }
  }
  __asm__ volatile("s_waitcnt lgkmcnt(0)" ::: "memory");

  v8h p0 = *(const v8h*)&tbuf[wv][l15][quad * 8];
  v8h p1 = *(const v8h*)&tbuf[wv][l15][32 + quad * 8];

  #pragma unroll
  for (int t = 0; t < 3; ++t) {
    f32x4_t o4 = {0.f, 0.f, 0.f, 0.f};
    o4 = __builtin_amdgcn_mfma_f32_16x16x32_f16(p0, bwf[t][0], o4, 0, 0, 0);
    o4 = __builtin_amdgcn_mfma_f32_16x16x32_f16(p1, bwf[t][1], o4, 0, 0, 0);
    int c = t * 16 + l15;
    if (c < 45) {
      #pragma unroll
      for (int r = 0; r < 4; ++r)
        out[(tile * 16 + quad * 4 + r) * 45 + c] = o4[r] + ob[t];
    }
  }
}

// ---------------- launch ----------------
extern "C" void kernel_launch(void* const* d_in, const int* in_sizes, int n_in,
                              void* d_out, int out_size, void* d_ws, size_t ws_size,
                              hipStream_t stream) {
  const float* x    = (const float*)d_in[0];
  const int*   ei   = (const int*)d_in[1];
  const float* Wz   = (const float*)d_in[2];
  const float* bz   = (const float*)d_in[3];
  const float* Wlz  = (const float*)d_in[4];
  const float* blz  = (const float*)d_in[5];
  // d_in[6..9] (W_r branch) dead: H=0 => H*R=0.
  const float* Wh   = (const float*)d_in[10];
  const float* bh   = (const float*)d_in[11];
  const float* Wlh  = (const float*)d_in[12];
  const float* blh  = (const float*)d_in[13];
  const float* Wout = (const float*)d_in[14];
  const float* bout = (const float*)d_in[15];
  float* out = (float*)d_out;

  char* w = (char*)d_ws;
  // bins (early) and sxg (late) alias: bins dead after k_sort.
  int*      bins  = (int*)(w + 0);            // 782*2560*4 = 8,007,680
  _Float16* sxg   = (_Float16*)(w + 0);       // 6,400,000 (alias)
  int*      gcur  = (int*)(w + 8007680);      // 3,128
  ushort_t* srcp  = (ushort_t*)(w + 8010816); // 782*3072*2 = 4,804,608
  int2*     rowiv = (int2*)(w + 12815424);    // 400,000
  float*    dinv  = (float*)(w + 13215424);   // 200,000
  float2*   B2    = (float2*)(w + 13415424);  // 512
  _Float16* Bzh   = (_Float16*)(w + 13415936);// 16,384
  _Float16* Bwo   = (_Float16*)(w + 13432320);// 6,144
  _Float16* xp    = (_Float16*)(w + 13438464);// 6,400,128 -> ends ~19.8 MB

  hipMemsetAsync(gcur, 0, NB * sizeof(int), stream);
  k_binw <<<NBB + 8, 256, 0, stream>>>(ei, gcur, bins, Wz, bz, Wlz, blz,
                                       Wh, bh, Wlh, blh, Wout,
                                       (float*)B2, Bzh, Bwo);
  k_sort <<<NB, 256, 0, stream>>>(bins, gcur, x, srcp, rowiv, dinv, xp);
  k_agg  <<<2048, 256, 0, stream>>>(srcp, rowiv, dinv, xp, sxg);
  k_cell <<<NB, 256, 0, stream>>>(sxg, Bzh, Bwo, B2, bout, out);
}

// Round 10
// 156.381 us; speedup vs baseline: 1.2625x; 1.0202x over previous
//
#include <hip/hip_runtime.h>

#define N_NODES 50000
#define N_EDGES 1600000
#define NB 782            // buckets of 64 dst nodes: ceil(50000/64)
#define NBB 256           // binning blocks
#define CHUNK 6250        // N_EDGES / NBB (exact, even)
#define CAP 2560          // fixed bucket capacity (mean 2046 + 11 sigma)
#define SCAP 3072         // srcp per-bucket capacity (CAP + pad slack)
#define ZROW 50000        // dummy src row (all zeros) for padding
#define NTILES 3125       // 50000 / 16 exact

typedef unsigned short ushort_t;
typedef _Float16 v8h __attribute__((ext_vector_type(8)));
typedef _Float16 v4h __attribute__((ext_vector_type(4)));
typedef _Float16 v2h __attribute__((ext_vector_type(2)));
typedef float f32x4_t __attribute__((ext_vector_type(4)));

// r10: k_agg drops ds_bpermute.  srcp[e+grp] is an 8-way-broadcast 2B load
// (L1-hot line reused 8x), so the gather chain is {index load -> xp load}
// instead of {coalesced load -> 120cy bpermute -> xp load}.  r4/r8/r9
// falsified issue-count / L2-capacity / VALU theories; the DS-latency chain
// is the last untested term.

// ========== fused binning + weight prep (independent block families) ======
__global__ __launch_bounds__(256) void k_binw(
    const int* __restrict__ ei, int* __restrict__ gcur, int* __restrict__ bins,
    const float* __restrict__ Wz, const float* __restrict__ bz,
    const float* __restrict__ Wlz, const float* __restrict__ blz,
    const float* __restrict__ Wh, const float* __restrict__ bh,
    const float* __restrict__ Wlh, const float* __restrict__ blh,
    const float* __restrict__ Wout, float* __restrict__ B2f,
    _Float16* __restrict__ Bzh, _Float16* __restrict__ Bwo) {
  __shared__ int arena[8320];   // bin: 2*NB+CHUNK=7814 ints; wprep: 8320 floats
  int tid = threadIdx.x, blk = blockIdx.x;
  if (blk < NBB) {
    int* h    = arena;          // 782
    int* segb = arena + NB;     // 782
    int* pk   = arena + 2 * NB; // 6250
    for (int i = tid; i < NB; i += 256) h[i] = 0;
    __syncthreads();
    const int2* s2 = (const int2*)(ei + blk * CHUNK);
    const int2* d2 = (const int2*)(ei + N_EDGES + blk * CHUNK);
    for (int i = tid; i < CHUNK / 2; i += 256) {
      int2 s = s2[i];
      int2 d = d2[i];
      pk[2 * i]     = s.x | ((d.x & 63) << 16) | ((d.x >> 6) << 22);
      pk[2 * i + 1] = s.y | ((d.y & 63) << 16) | ((d.y >> 6) << 22);
      atomicAdd(&h[d.x >> 6], 1);
      atomicAdd(&h[d.y >> 6], 1);
    }
    __syncthreads();
    for (int b = tid; b < NB; b += 256) {
      int c = h[b];
      segb[b] = c ? atomicAdd(&gcur[b], c) : 0;
      h[b] = 0;                       // reuse as local cursor
    }
    __syncthreads();
    for (int i = tid; i < CHUNK; i += 256) {
      int v = pk[i];
      int b = (unsigned)v >> 22;
      int p = atomicAdd(&h[b], 1);
      bins[b * CAP + segb[b] + p] = v & 0x3FFFFF;   // src | dl<<16
    }
  } else {
    // weight prep: wblk 0-3 z-path, 4-7 h-path; ntile = wblk&3
    int wblk = blk - NBB;
    float* A  = (float*)arena;           // 64x65
    float* Bm = (float*)(arena + 4160);  // 64x65
    bool zpath = wblk < 4;
    const float* Wsrc = zpath ? Wz : Wh;
    const float* Lsrc = zpath ? Wlz : Wlh;
    for (int idx = tid; idx < 4096; idx += 256) {
      A[(idx >> 6) * 65 + (idx & 63)] = Wsrc[idx];
      Bm[(idx >> 6) * 65 + (idx & 63)] = Lsrc[idx];
    }
    __syncthreads();
    int lane = (tid >> 1) & 63;
    int j0 = (tid & 1) * 4;
    int ks = (tid >> 7) & 1;
    int k0 = ks * 32 + ((lane >> 4) << 3) + j0;
    int col = (wblk & 3) * 16 + (lane & 15);
    float a0 = 0.f, a1 = 0.f, a2 = 0.f, a3 = 0.f;
    for (int q = 0; q < 64; ++q) {
      float bv = Bm[q * 65 + col];
      a0 = fmaf(A[k0 * 65 + q], bv, a0);
      a1 = fmaf(A[(k0 + 1) * 65 + q], bv, a1);
      a2 = fmaf(A[(k0 + 2) * 65 + q], bv, a2);
      a3 = fmaf(A[(k0 + 3) * 65 + q], bv, a3);
    }
    int tb = wblk * 1024 + tid * 4;
    v4h o; o[0] = (_Float16)a0; o[1] = (_Float16)a1;
    o[2] = (_Float16)a2; o[3] = (_Float16)a3;
    *(v4h*)(Bzh + tb) = o;
    if ((wblk == 0 || wblk == 4) && tid < 64) {
      float v = zpath ? blz[tid] : blh[tid];
      const float* bb = zpath ? bz : bh;
      for (int q = 0; q < 64; ++q) v = fmaf(bb[q], Bm[q * 65 + tid], v);
      B2f[tid * 2 + (zpath ? 0 : 1)] = v;
    }
    if (wblk == 1) {
      for (int e2 = 0; e2 < 12; ++e2) {
        int t2 = tid * 12 + e2;
        int ln = (t2 >> 3) & 63, j = t2 & 7;
        int ntile = t2 >> 10, ks2 = (t2 >> 9) & 1;
        int n = ntile * 16 + (ln & 15);
        int k = ks2 * 32 + ((ln >> 4) << 3) + j;
        Bwo[t2] = (_Float16)((n < 45) ? Wout[k * 45 + n] : 0.f);
      }
    }
  }
}

// ---------------- per-bucket sort -> padded per-node CSR + dinv + xp -------
__global__ __launch_bounds__(256, 4) void k_sort(
    const int* __restrict__ bins, const int* __restrict__ gcur,
    const float* __restrict__ x,
    ushort_t* __restrict__ srcp, int2* __restrict__ rowiv,
    float* __restrict__ dinv, _Float16* __restrict__ xp) {
  __shared__ int dg[64], lo[64], cur[64];
  __shared__ float sdin[64];
  __shared__ int Tsh;
  __shared__ ushort_t buf[8192];
  int tid = threadIdx.x, b = blockIdx.x;
  int start = b * CAP, end = start + gcur[b];
  if (tid < 64) dg[tid] = 0;
  __syncthreads();
  for (int i = start + tid; i < end; i += 256)
    atomicAdd(&dg[bins[i] >> 16], 1);
  __syncthreads();
  int pdv = 0;
  if (tid < 64) { pdv = (dg[tid] + 7) & ~7; lo[tid] = pdv; }
  __syncthreads();
  for (int off = 1; off < 64; off <<= 1) {
    int u = 0;
    if (tid < 64 && tid >= off) u = lo[tid - off];
    __syncthreads();
    if (tid < 64) lo[tid] += u;
    __syncthreads();
  }
  int ex = 0;
  if (tid < 64) {
    ex = lo[tid] - pdv;       // exclusive padded offset
    cur[tid] = ex;
    if (tid == 63) Tsh = lo[63];
  }
  __syncthreads();
  int T = Tsh;
  int base = b * SCAP;        // fixed per-bucket srcp region
  for (int i = tid; i < T; i += 256) buf[i] = (ushort_t)ZROW;
  __syncthreads();
  for (int i = start + tid; i < end; i += 256) {
    int v = bins[i];
    int dl = v >> 16;
    int p = atomicAdd(&cur[dl], 1);
    buf[p] = (ushort_t)(v & 0xFFFF);
  }
  __syncthreads();
  for (int i = tid; i < T; i += 256) srcp[base + i] = buf[i];
  if (tid < 64) {
    int v = b * 64 + tid;
    if (v < N_NODES) {
      rowiv[v] = make_int2(base + ex, pdv);
      float dv = rsqrtf((float)dg[tid] + 2.0f);
      dinv[v] = dv;
      sdin[tid] = dv;
    } else {
      sdin[tid] = 0.f;
    }
  }
  __syncthreads();
  // vectorized x -> xp (float4 in, v4h out)
  const float4* x4 = (const float4*)x;
  int base4 = b * 1024;           // float4 index of bucket start
  int nb64 = b * 4096;            // half index of bucket start
  for (int idx = tid; idx < 1024; idx += 256) {
    int row = idx >> 4;           // 16 float4 per 64-ch row
    int v = b * 64 + row;
    if (v < N_NODES) {
      float4 xv = x4[base4 + idx];
      float s = sdin[row];
      v4h o;
      o[0] = (_Float16)(s * xv.x); o[1] = (_Float16)(s * xv.y);
      o[2] = (_Float16)(s * xv.z); o[3] = (_Float16)(s * xv.w);
      *(v4h*)(xp + nb64 + idx * 4) = o;
    }
  }
  if (b == 0 && tid < 64) xp[ZROW * 64 + tid] = (_Float16)0.f;
}

// ------- gather: direct broadcast srcp loads (no bpermute), 4-deep ---------
// 8 lanes per edge x 16B; lane's edge slot grp=lane>>3 reads srcp[e+grp]
// directly (8-way broadcast, L1-hot).  beg/pd multiples of 8; srcp is
// ZROW-padded so no masking needed.
__global__ __launch_bounds__(256, 8) void k_agg(
    const ushort_t* __restrict__ srcp, const int2* __restrict__ rowiv,
    const float* __restrict__ dinv, const _Float16* __restrict__ xp,
    _Float16* __restrict__ sxg) {
  int tid = threadIdx.x;
  int lane = tid & 63;
  int grp = lane >> 3;          // edge slot 0..7
  int chOff = (lane & 7) << 3;  // channels (lane&7)*8 .. +7
  const v2h onE = {(_Float16)1.0f, (_Float16)0.0f};
  const v2h onO = {(_Float16)0.0f, (_Float16)1.0f};
  int w = blockIdx.x * 4 + (tid >> 6);
  int nw = gridDim.x * 4;
  for (int v = w; v < N_NODES; v += nw) {
    int vu = __builtin_amdgcn_readfirstlane(v);
    int2 ri = rowiv[vu];
    int beg = ri.x, pd = ri.y;    // both multiples of 8
    float aE[2][4], aO[2][4];     // [set][pair]
    #pragma unroll
    for (int j = 0; j < 4; ++j) {
      aE[0][j] = 0.f; aE[1][j] = 0.f; aO[0][j] = 0.f; aO[1][j] = 0.f;
    }
    int e = beg, eend = beg + pd;
    for (; e + 32 <= eend; e += 32) {   // 4 groups of 8 edges in flight
      int s0 = (int)srcp[e + grp];
      int s1 = (int)srcp[e + 8 + grp];
      int s2 = (int)srcp[e + 16 + grp];
      int s3 = (int)srcp[e + 24 + grp];
      v8h r0 = *(const v8h*)(xp + (s0 << 6) + chOff);
      v8h r1 = *(const v8h*)(xp + (s1 << 6) + chOff);
      v8h r2 = *(const v8h*)(xp + (s2 << 6) + chOff);
      v8h r3 = *(const v8h*)(xp + (s3 << 6) + chOff);
      const v2h* p0 = (const v2h*)&r0;
      const v2h* p1 = (const v2h*)&r1;
      const v2h* p2 = (const v2h*)&r2;
      const v2h* p3 = (const v2h*)&r3;
      #pragma unroll
      for (int j = 0; j < 4; ++j) {
        aE[0][j] = __builtin_amdgcn_fdot2(p0[j], onE, aE[0][j], false);
        aO[0][j] = __builtin_amdgcn_fdot2(p0[j], onO, aO[0][j], false);
        aE[1][j] = __builtin_amdgcn_fdot2(p1[j], onE, aE[1][j], false);
        aO[1][j] = __builtin_amdgcn_fdot2(p1[j], onO, aO[1][j], false);
        aE[0][j] = __builtin_amdgcn_fdot2(p2[j], onE, aE[0][j], false);
        aO[0][j] = __builtin_amdgcn_fdot2(p2[j], onO, aO[0][j], false);
        aE[1][j] = __builtin_amdgcn_fdot2(p3[j], onE, aE[1][j], false);
        aO[1][j] = __builtin_amdgcn_fdot2(p3[j], onO, aO[1][j], false);
      }
    }
    for (; e < eend; e += 8) {          // 0-3 tail groups
      int s0 = (int)srcp[e + grp];
      v8h r0 = *(const v8h*)(xp + (s0 << 6) + chOff);
      const v2h* p0 = (const v2h*)&r0;
      #pragma unroll
      for (int j = 0; j < 4; ++j) {
        aE[0][j] = __builtin_amdgcn_fdot2(p0[j], onE, aE[0][j], false);
        aO[0][j] = __builtin_amdgcn_fdot2(p0[j], onO, aO[0][j], false);
      }
    }
    float a[8];
    #pragma unroll
    for (int j = 0; j < 4; ++j) {
      a[2 * j]     = aE[0][j] + aE[1][j];
      a[2 * j + 1] = aO[0][j] + aO[1][j];
    }
    // reduce over the 8 edge-slots (lane bits 3..5)
    #pragma unroll
    for (int j = 0; j < 8; ++j) {
      a[j] += __shfl_xor(a[j], 8);
      a[j] += __shfl_xor(a[j], 16);
      a[j] += __shfl_xor(a[j], 32);
    }
    if (lane < 8) {
      float dv = dinv[vu];
      v8h self = *(const v8h*)(xp + (vu << 6) + chOff);
      v8h o;
      #pragma unroll
      for (int j = 0; j < 8; ++j)
        o[j] = (_Float16)(dv * a[j] + 2.f * dv * (float)self[j]);
      *(v8h*)(sxg + (vu << 6) + chOff) = o;
    }
  }
}

// ---------------- MFMA cell + readout (one wave per 16-node tile) ----------
__global__ __launch_bounds__(256) void k_cell(
    const _Float16* __restrict__ sxg, const _Float16* __restrict__ Bzh,
    const _Float16* __restrict__ Bwo, const float2* __restrict__ B2,
    const float* __restrict__ bout, float* __restrict__ out) {
  __shared__ __align__(16) _Float16 tbuf[4][16][72];
  int tid = threadIdx.x;
  int lane = tid & 63, wv = tid >> 6;
  int l15 = lane & 15, quad = lane >> 4;
  int tile = blockIdx.x * 4 + wv;
  if (tile >= NTILES) return;    // no barriers in this kernel -> safe

  v8h bzf[8][2], bwf[3][2];
  #pragma unroll
  for (int t = 0; t < 8; ++t)
    #pragma unroll
    for (int ks = 0; ks < 2; ++ks)
      bzf[t][ks] = *(const v8h*)(Bzh + (((t * 2 + ks) * 64 + lane) << 3));
  #pragma unroll
  for (int t = 0; t < 3; ++t)
    #pragma unroll
    for (int ks = 0; ks < 2; ++ks)
      bwf[t][ks] = *(const v8h*)(Bwo + (((t * 2 + ks) * 64 + lane) << 3));
  float zb[4], hb[4], ob[3];
  #pragma unroll
  for (int t = 0; t < 4; ++t) {
    float2 bb = B2[t * 16 + l15];
    zb[t] = bb.x; hb[t] = bb.y;
  }
  #pragma unroll
  for (int t = 0; t < 3; ++t) {
    int c = t * 16 + l15;
    ob[t] = (c < 45) ? bout[c] : 0.f;
  }

  const _Float16* ar = sxg + (tile * 16 + l15) * 64 + quad * 8;
  v8h a0 = *(const v8h*)ar;
  v8h a1 = *(const v8h*)(ar + 32);

  f32x4_t accz[8];
  #pragma unroll
  for (int t = 0; t < 8; ++t) {
    f32x4_t c4 = {0.f, 0.f, 0.f, 0.f};
    c4 = __builtin_amdgcn_mfma_f32_16x16x32_f16(a0, bzf[t][0], c4, 0, 0, 0);
    c4 = __builtin_amdgcn_mfma_f32_16x16x32_f16(a1, bzf[t][1], c4, 0, 0, 0);
    accz[t] = c4;
  }

  #pragma unroll
  for (int t = 0; t < 4; ++t) {
    #pragma unroll
    for (int r = 0; r < 4; ++r) {
      float zv = accz[t][r] + zb[t];
      float hv = accz[t + 4][r] + hb[t];
      float Z = 1.f / (1.f + __expf(-zv));
      float tt = fminf(15.f, fmaxf(-15.f, hv));
      float e2 = __expf(-2.f * tt);
      float Th = (1.f - e2) / (1.f + e2);
      tbuf[wv][quad * 4 + r][t * 16 + l15] = (_Float16)fmaxf((1.f - Z) * Th, 0.f);
    }
  }
  __asm__ volatile("s_waitcnt lgkmcnt(0)" ::: "memory");

  v8h p0 = *(const v8h*)&tbuf[wv][l15][quad * 8];
  v8h p1 = *(const v8h*)&tbuf[wv][l15][32 + quad * 8];

  #pragma unroll
  for (int t = 0; t < 3; ++t) {
    f32x4_t o4 = {0.f, 0.f, 0.f, 0.f};
    o4 = __builtin_amdgcn_mfma_f32_16x16x32_f16(p0, bwf[t][0], o4, 0, 0, 0);
    o4 = __builtin_amdgcn_mfma_f32_16x16x32_f16(p1, bwf[t][1], o4, 0, 0, 0);
    int c = t * 16 + l15;
    if (c < 45) {
      #pragma unroll
      for (int r = 0; r < 4; ++r)
        out[(tile * 16 + quad * 4 + r) * 45 + c] = o4[r] + ob[t];
    }
  }
}

// ---------------- launch ----------------
extern "C" void kernel_launch(void* const* d_in, const int* in_sizes, int n_in,
                              void* d_out, int out_size, void* d_ws, size_t ws_size,
                              hipStream_t stream) {
  const float* x    = (const float*)d_in[0];
  const int*   ei   = (const int*)d_in[1];
  const float* Wz   = (const float*)d_in[2];
  const float* bz   = (const float*)d_in[3];
  const float* Wlz  = (const float*)d_in[4];
  const float* blz  = (const float*)d_in[5];
  // d_in[6..9] (W_r branch) dead: H=0 => H*R=0.
  const float* Wh   = (const float*)d_in[10];
  const float* bh   = (const float*)d_in[11];
  const float* Wlh  = (const float*)d_in[12];
  const float* blh  = (const float*)d_in[13];
  const float* Wout = (const float*)d_in[14];
  const float* bout = (const float*)d_in[15];
  float* out = (float*)d_out;

  char* w = (char*)d_ws;
  // bins (early) and sxg (late) alias: bins dead after k_sort.
  int*      bins  = (int*)(w + 0);            // 782*2560*4 = 8,007,680
  _Float16* sxg   = (_Float16*)(w + 0);       // 6,400,000 (alias)
  int*      gcur  = (int*)(w + 8007680);      // 3,128
  ushort_t* srcp  = (ushort_t*)(w + 8010816); // 782*3072*2 = 4,804,608
  int2*     rowiv = (int2*)(w + 12815424);    // 400,000
  float*    dinv  = (float*)(w + 13215424);   // 200,000
  float2*   B2    = (float2*)(w + 13415424);  // 512
  _Float16* Bzh   = (_Float16*)(w + 13415936);// 16,384
  _Float16* Bwo   = (_Float16*)(w + 13432320);// 6,144
  _Float16* xp    = (_Float16*)(w + 13438464);// 6,400,128 -> ends ~19.8 MB

  hipMemsetAsync(gcur, 0, NB * sizeof(int), stream);
  k_binw <<<NBB + 8, 256, 0, stream>>>(ei, gcur, bins, Wz, bz, Wlz, blz,
                                       Wh, bh, Wlh, blh, Wout,
                                       (float*)B2, Bzh, Bwo);
  k_sort <<<NB, 256, 0, stream>>>(bins, gcur, x, srcp, rowiv, dinv, xp);
  k_agg  <<<2048, 256, 0, stream>>>(srcp, rowiv, dinv, xp, sxg);
  k_cell <<<NB, 256, 0, stream>>>(sxg, Bzh, Bwo, B2, bout, out);
}